// Round 2
// baseline (131.825 us; speedup 1.0000x reference)
//
#include <hip/hip_runtime.h>
#include <math.h>

#define T_DIM 256
#define C_DIM 128
#define H_DIM 64

typedef __attribute__((ext_vector_type(8))) short short8v;
typedef __attribute__((ext_vector_type(4))) short short4v;
typedef __attribute__((ext_vector_type(4))) float float4v;

// LDS layout (element = short/bf16), XOR-swizzled 16B slots:
//  K  [256][64] @ 0      (16384 el, 32 KB)  slot ^= row&7
//  VT [64][256] @ 16384  (16384 el, 32 KB)  slot ^= h&7
//  P  [8][32][17] @ 32768 (4352 el, 8.5 KB) per-wave P^T relayout
//  total 37120 shorts = 74240 B -> 2 blocks/CU
//  olds float[256][64] (swizzled) aliases K+VT exactly for output transpose
#define K_OFF 0
#define VT_OFF 16384
#define P_OFF 32768
#define SMEM_BYTES 74240

static __device__ __forceinline__ short f2bf(float f) {
  union { float f; unsigned u; } x; x.f = f;
  unsigned r = x.u + 0x7FFFu + ((x.u >> 16) & 1u);  // RNE
  return (short)(r >> 16);
}

// swizzled element addresses (16B-slot XOR keeps b128 alignment)
static __device__ __forceinline__ int kaddr(int row, int col) {
  return row * 64 + ((((col >> 3) ^ (row & 7))) << 3) + (col & 7);
}
static __device__ __forceinline__ int vaddr(int h, int t) {
  return h * 256 + ((((t >> 3) ^ (h & 7))) << 3) + (t & 7);
}

// prep: W[c][h] fp32 -> wt[p][h][c] bf16 (48 KB in d_ws, L2-resident)
__global__ void prep_w(const float* __restrict__ Wq, const float* __restrict__ Wk,
                       const float* __restrict__ Wv, short* __restrict__ wt) {
  int t = blockIdx.x * 256 + threadIdx.x;   // 6144 threads
  int p = t >> 11;                          // 0..2
  int i4 = t & 2047;                        // float4 index in W (2048 per W)
  const float* W = (p == 0) ? Wq : (p == 1) ? Wk : Wv;
  float4v v = *(const float4v*)(W + i4 * 4);
  int c = i4 >> 4;
  int h0 = (i4 & 15) * 4;
  short* base = wt + p * 8192 + c;          // element (h,c) at h*128+c
  base[(h0 + 0) * 128] = f2bf(v.x);
  base[(h0 + 1) * 128] = f2bf(v.y);
  base[(h0 + 2) * 128] = f2bf(v.z);
  base[(h0 + 3) * 128] = f2bf(v.w);
}

__global__ __launch_bounds__(512, 4) void head_fused(
    const float* __restrict__ x, const short* __restrict__ wt,
    float* __restrict__ out)
{
  extern __shared__ __align__(16) short sm[];
  const int b   = blockIdx.x;
  const int tid = threadIdx.x;
  const int w   = tid >> 6;   // wave 0..7
  const int l   = tid & 63;
  const int il  = l & 15;
  const int g   = l >> 4;

  const float SCL2 = 0.12751744f;  // C^-0.5 * log2(e), folded into Q
  int tqs[2]; tqs[0] = w; tqs[1] = 15 - w;   // balanced causal work
  const float* xb = x + (size_t)b * (T_DIM * C_DIM);

  short8v qf[2][2];

  // ---------- phase 1: projections (per-wave: its 2 query tiles' rows) ----------
#pragma unroll
  for (int tt = 0; tt < 2; ++tt) {
    const int tq = tqs[tt];
    // x A-fragments for rows [tq*16, tq*16+16)
    short8v xa[4];
#pragma unroll
    for (int ks = 0; ks < 4; ++ks) {
      const float* src = xb + (tq * 16 + il) * C_DIM + ks * 32 + g * 8;
      float4v a0 = *(const float4v*)src;
      float4v a1 = *(const float4v*)(src + 4);
      short8v f;
      f[0] = f2bf(a0.x); f[1] = f2bf(a0.y); f[2] = f2bf(a0.z); f[3] = f2bf(a0.w);
      f[4] = f2bf(a1.x); f[5] = f2bf(a1.y); f[6] = f2bf(a1.z); f[7] = f2bf(a1.w);
      xa[ks] = f;
    }
#pragma unroll
    for (int p = 0; p < 3; ++p) {
#pragma unroll
      for (int ht = 0; ht < 4; ++ht) {
        short8v wb[4];
#pragma unroll
        for (int ks = 0; ks < 4; ++ks)
          wb[ks] = *(const short8v*)(wt + (p * 64 + ht * 16 + il) * 128 + ks * 32 + g * 8);
        float4v acc = {0.f, 0.f, 0.f, 0.f};
#pragma unroll
        for (int ks = 0; ks < 4; ++ks)
          acc = __builtin_amdgcn_mfma_f32_16x16x32_bf16(xa[ks], wb[ks], acc, 0, 0, 0);
        if (p == 0) {
          // stash scaled Q (bf16) transiently in this tile's K rows
#pragma unroll
          for (int r = 0; r < 4; ++r)
            sm[K_OFF + kaddr(tq * 16 + g * 4 + r, ht * 16 + il)] = f2bf(acc[r] * SCL2);
        } else if (p == 1) {
#pragma unroll
          for (int r = 0; r < 4; ++r)
            sm[K_OFF + kaddr(tq * 16 + g * 4 + r, ht * 16 + il)] = f2bf(acc[r]);
        } else {
          short4v pk;
#pragma unroll
          for (int r = 0; r < 4; ++r) pk[r] = f2bf(acc[r]);
          *(short4v*)&sm[VT_OFF + vaddr(ht * 16 + il, tq * 16 + g * 4)] = pk;
        }
      }
      if (p == 0) {
        // read Q B-fragments out of the stash before K overwrites it (same wave)
#pragma unroll
        for (int hk = 0; hk < 2; ++hk)
          qf[tt][hk] = *(const short8v*)&sm[K_OFF + kaddr(tq * 16 + il, hk * 32 + g * 8)];
      }
    }
  }
  __syncthreads();

  // ---------- phase 2: causal flash attention ----------
  float4v oacc[2][4];
  const int pbase = P_OFF + w * 544;   // 544 = 32*17

#pragma unroll
  for (int tt = 0; tt < 2; ++tt) {
    const int tq    = tqs[tt];
    const int i_row = tq * 16 + il;
    float mr = -INFINITY, lr = 0.f;
    float4v oa0 = {0.f,0.f,0.f,0.f}, oa1 = oa0, oa2 = oa0, oa3 = oa0;
    const int nblk = (tq >> 2) + 1;
    for (int jb = 0; jb < nblk; ++jb) {
      // S^T = K . Q^T (Q pre-scaled); lane holds S^T[j=jb*64+jt*16+g*4+r][i=il]
      float s[4][4];
#pragma unroll
      for (int jt = 0; jt < 4; ++jt) {
        const int rb = jb * 64 + jt * 16 + il;
        short8v kf0 = *(const short8v*)&sm[K_OFF + rb * 64 + ((g ^ (il & 7)) << 3)];
        short8v kf1 = *(const short8v*)&sm[K_OFF + rb * 64 + (((4 + g) ^ (il & 7)) << 3)];
        float4v a = {0.f, 0.f, 0.f, 0.f};
        a = __builtin_amdgcn_mfma_f32_16x16x32_bf16(kf0, qf[tt][0], a, 0, 0, 0);
        a = __builtin_amdgcn_mfma_f32_16x16x32_bf16(kf1, qf[tt][1], a, 0, 0, 0);
        s[jt][0] = a[0]; s[jt][1] = a[1]; s[jt][2] = a[2]; s[jt][3] = a[3];
      }
      const bool diag = (jb == (tq >> 2));
      float bm = -INFINITY;
#pragma unroll
      for (int jt = 0; jt < 4; ++jt)
#pragma unroll
        for (int r = 0; r < 4; ++r) {
          float v = s[jt][r];
          if (diag && (jb * 64 + jt * 16 + g * 4 + r) > i_row) v = -INFINITY;
          s[jt][r] = v;
          bm = fmaxf(bm, v);
        }
      bm = fmaxf(bm, __shfl_xor(bm, 16));
      bm = fmaxf(bm, __shfl_xor(bm, 32));
      const float mn = fmaxf(mr, bm);
      const float rs = exp2f(mr - mn);
      float tot = 0.f;
#pragma unroll
      for (int jt = 0; jt < 4; ++jt)
#pragma unroll
        for (int r = 0; r < 4; ++r) {
          float pv = exp2f(s[jt][r] - mn);
          s[jt][r] = pv;
          tot += pv;
        }
      tot += __shfl_xor(tot, 16);
      tot += __shfl_xor(tot, 32);
      lr = lr * rs + tot;
      mr = mn;
      oa0 *= rs; oa1 *= rs; oa2 *= rs; oa3 *= rs;

      // PV in two 32-key halves: P^T relayout via per-wave LDS, O^T = V^T . P^T
#pragma unroll
      for (int half = 0; half < 2; ++half) {
#pragma unroll
        for (int jt2 = 0; jt2 < 2; ++jt2)
#pragma unroll
          for (int r = 0; r < 4; ++r)
            sm[pbase + (jt2 * 16 + g * 4 + r) * 17 + il] = f2bf(s[half * 2 + jt2][r]);
        short8v pf;
#pragma unroll
        for (int jj = 0; jj < 8; ++jj)
          pf[jj] = sm[pbase + (g * 8 + jj) * 17 + il];
        const int cb = jb * 64 + half * 32 + g * 8;
        const int sl = ((cb >> 3) ^ (il & 7)) << 3;
        {
          short8v vf = *(const short8v*)&sm[VT_OFF + (0 * 16 + il) * 256 + sl];
          oa0 = __builtin_amdgcn_mfma_f32_16x16x32_bf16(vf, pf, oa0, 0, 0, 0);
        }
        {
          short8v vf = *(const short8v*)&sm[VT_OFF + (1 * 16 + il) * 256 + sl];
          oa1 = __builtin_amdgcn_mfma_f32_16x16x32_bf16(vf, pf, oa1, 0, 0, 0);
        }
        {
          short8v vf = *(const short8v*)&sm[VT_OFF + (2 * 16 + il) * 256 + sl];
          oa2 = __builtin_amdgcn_mfma_f32_16x16x32_bf16(vf, pf, oa2, 0, 0, 0);
        }
        {
          short8v vf = *(const short8v*)&sm[VT_OFF + (3 * 16 + il) * 256 + sl];
          oa3 = __builtin_amdgcn_mfma_f32_16x16x32_bf16(vf, pf, oa3, 0, 0, 0);
        }
      }
    }
    const float inv = 1.f / lr;
    oa0 *= inv; oa1 *= inv; oa2 *= inv; oa3 *= inv;
    oacc[tt][0] = oa0; oacc[tt][1] = oa1; oacc[tt][2] = oa2; oacc[tt][3] = oa3;
  }

  // ---------- phase 3: transpose O via LDS (swizzled), coalesced store ----------
  __syncthreads();                      // all waves done reading K/VT
  float* olds = (float*)sm;             // [256][64] f32, 16B-slot swizzle
#pragma unroll
  for (int tt = 0; tt < 2; ++tt) {
    int i = tqs[tt] * 16 + il;
#pragma unroll
    for (int ht = 0; ht < 4; ++ht)
      *(float4v*)&olds[i * 64 + (((ht * 4 + g) ^ (i & 7)) << 2)] = oacc[tt][ht];
  }
  __syncthreads();
  float* outb = out + (size_t)b * (T_DIM * H_DIM);
#pragma unroll
  for (int k = 0; k < 8; ++k) {
    int idx = k * 512 + tid;            // 0..4095 float4s
    int row = idx >> 4;
    int sc  = (idx & 15) ^ (row & 7);
    *(float4v*)(outb + idx * 4) = *(const float4v*)&olds[row * 64 + (sc << 2)];
  }
}

extern "C" void kernel_launch(void* const* d_in, const int* in_sizes, int n_in,
                              void* d_out, int out_size, void* d_ws, size_t ws_size,
                              hipStream_t stream) {
  const float* x  = (const float*)d_in[0];
  const float* Wq = (const float*)d_in[1];
  const float* Wk = (const float*)d_in[2];
  const float* Wv = (const float*)d_in[3];
  float* out = (float*)d_out;
  short* wt = (short*)d_ws;   // 48 KB bf16 transposed weights
  prep_w<<<dim3(24), dim3(256), 0, stream>>>(Wq, Wk, Wv, wt);
  hipFuncSetAttribute((const void*)head_fused,
                      hipFuncAttributeMaxDynamicSharedMemorySize, SMEM_BYTES);
  head_fused<<<dim3(1024), dim3(512), SMEM_BYTES, stream>>>(x, wt, out);
}

// Round 4
// 89.016 us; speedup vs baseline: 1.4809x; 1.4809x over previous
//
#include <hip/hip_runtime.h>
#include <math.h>

#define T_DIM 256
#define C_DIM 128
#define H_DIM 64

typedef __attribute__((ext_vector_type(8))) short short8v;
typedef __attribute__((ext_vector_type(4))) short short4v;
typedef __attribute__((ext_vector_type(4))) float float4v;

// LDS: K [256][64] @0 (32KB, rows PERMUTED within 64-blocks, 16B-slot XOR swizzle)
//      VT [64][256] @16384 (32KB, true t, swizzled)   -> 64KB, 2 blocks/CU
// olds float[256][64] aliases the whole thing for the output transpose.
#define K_OFF 0
#define VT_OFF 16384
#define SMEM_BYTES 65536

static __device__ __forceinline__ short f2bf(float f) {
  union { float f; unsigned u; } x; x.f = f;
  unsigned r = x.u + 0x7FFFu + ((x.u >> 16) & 1u);  // RNE
  return (short)(r >> 16);
}

// storage-row permutation within a 64-row block:
// row' such that QK^T D-layout delivers J = (jt&1)*32 + g*8 + (jt>>1)*4 + r
static __device__ __forceinline__ int permrow(int J) {
  return ((J >> 5) + ((J >> 2) & 1) * 2) * 16 + (((J >> 3) & 3) << 2) + (J & 3);
}

static __device__ __forceinline__ int kaddr(int row, int col) {
  return row * 64 + ((((col >> 3) ^ (row & 7))) << 3) + (col & 7);
}
static __device__ __forceinline__ int vaddr(int h, int t) {
  return h * 256 + ((((t >> 3) ^ (h & 7))) << 3) + (t & 7);
}

// prep: W[c][h] f32 -> wt[p][h][c] bf16 (48KB in d_ws). Q rows permuted + pre-scaled.
__global__ void prep_w(const float* __restrict__ Wq, const float* __restrict__ Wk,
                       const float* __restrict__ Wv, short* __restrict__ wt) {
  const float SCL2 = 0.12751744f;  // C^-0.5 * log2(e) folded into Wq
  int t = blockIdx.x * 256 + threadIdx.x;   // 6144 threads
  int p = t >> 11;
  int i4 = t & 2047;
  const float* W = (p == 0) ? Wq : (p == 1) ? Wk : Wv;
  float4v v = *(const float4v*)(W + i4 * 4);
  if (p == 0) { v.x *= SCL2; v.y *= SCL2; v.z *= SCL2; v.w *= SCL2; }
  int c = i4 >> 4;
  int h0 = (i4 & 15) * 4;
  float vv[4] = {v.x, v.y, v.z, v.w};
#pragma unroll
  for (int j = 0; j < 4; ++j) {
    int h = h0 + j;
    int hr = (p == 0) ? permrow(h) : h;
    wt[p * 8192 + hr * 128 + c] = f2bf(vv[j]);
  }
}

__global__ __launch_bounds__(512, 4) void head_fused(
    const float* __restrict__ x, const short* __restrict__ wt,
    float* __restrict__ out)
{
  extern __shared__ __align__(16) short sm[];
  const int b   = blockIdx.x;
  const int tid = threadIdx.x;
  const int w   = tid >> 6;
  const int l   = tid & 63;
  const int il  = l & 15;
  const int g   = l >> 4;

  int tqs[2]; tqs[0] = w; tqs[1] = 15 - w;   // balanced causal work
  const float* xb = x + (size_t)b * (T_DIM * C_DIM);

  // ---------- phase 1: projections ----------
  // x A/B-fragments for both tiles (identical layout serves both roles)
  short8v xa[2][4];
#pragma unroll
  for (int tt = 0; tt < 2; ++tt) {
    int t0 = tqs[tt] * 16;
#pragma unroll
    for (int ks = 0; ks < 4; ++ks) {
      const float* src = xb + (t0 + il) * C_DIM + ks * 32 + g * 8;
      float4v a0 = *(const float4v*)src;
      float4v a1 = *(const float4v*)(src + 4);
      short8v f;
      f[0] = f2bf(a0.x); f[1] = f2bf(a0.y); f[2] = f2bf(a0.z); f[3] = f2bf(a0.w);
      f[4] = f2bf(a1.x); f[5] = f2bf(a1.y); f[6] = f2bf(a1.z); f[7] = f2bf(a1.w);
      xa[tt][ks] = f;
    }
  }

  short8v qf[2][2];
  {
    // p=0: Q^T = Wq^T_perm . x^T  (W as A-frag, x as B-frag) -> qf in-register
    float4v accQ[2][4];
#pragma unroll
    for (int ht = 0; ht < 4; ++ht) {
      short8v wb[4];
#pragma unroll
      for (int ks = 0; ks < 4; ++ks)
        wb[ks] = *(const short8v*)(wt + (ht * 16 + il) * 128 + ks * 32 + g * 8);
#pragma unroll
      for (int tt = 0; tt < 2; ++tt) {
        float4v acc = {0.f, 0.f, 0.f, 0.f};
#pragma unroll
        for (int ks = 0; ks < 4; ++ks)
          acc = __builtin_amdgcn_mfma_f32_16x16x32_bf16(wb[ks], xa[tt][ks], acc, 0, 0, 0);
        accQ[tt][ht] = acc;
      }
    }
    // qf[tt][hk][jj]: h = hk*32 + g*8 + jj -> acc tile (hk + 2*(jj>>2)), elem jj&3
#pragma unroll
    for (int tt = 0; tt < 2; ++tt)
#pragma unroll
      for (int hk = 0; hk < 2; ++hk) {
        short8v f;
#pragma unroll
        for (int r = 0; r < 4; ++r) {
          f[r]     = f2bf(accQ[tt][hk][r]);
          f[r + 4] = f2bf(accQ[tt][hk + 2][r]);
        }
        qf[tt][hk] = f;
      }
  }

  // p=1 (K, stored row-permuted), p=2 (V, stored transposed)
#pragma unroll
  for (int p = 1; p < 3; ++p) {
#pragma unroll
    for (int ht = 0; ht < 4; ++ht) {
      short8v wb[4];
#pragma unroll
      for (int ks = 0; ks < 4; ++ks)
        wb[ks] = *(const short8v*)(wt + (p * 64 + ht * 16 + il) * 128 + ks * 32 + g * 8);
#pragma unroll
      for (int tt = 0; tt < 2; ++tt) {
        float4v acc = {0.f, 0.f, 0.f, 0.f};
#pragma unroll
        for (int ks = 0; ks < 4; ++ks)
          acc = __builtin_amdgcn_mfma_f32_16x16x32_bf16(xa[tt][ks], wb[ks], acc, 0, 0, 0);
        const int tq = tqs[tt];
        if (p == 1) {
          // t = tq*16 + g*4 + r; J = t&63; store at (t>>6)*64 + permrow(J)
          int row0 = (tq >> 2) * 64 + (((tq & 3) >> 1) + ((g & 1) << 1)) * 16
                   + (((((tq & 3) << 1) + (g >> 1)) & 3) << 2);
          int col = ht * 16 + il;
#pragma unroll
          for (int r = 0; r < 4; ++r)
            sm[K_OFF + kaddr(row0 + r, col)] = f2bf(acc[r]);
        } else {
          short4v pk;
#pragma unroll
          for (int r = 0; r < 4; ++r) pk[r] = f2bf(acc[r]);
          *(short4v*)&sm[VT_OFF + vaddr(ht * 16 + il, tq * 16 + g * 4)] = pk;
        }
      }
    }
  }
  __syncthreads();

  // ---------- phase 2: causal flash attention (no LDS P round-trip) ----------
  float4v oacc[2][4];
#pragma unroll
  for (int tt = 0; tt < 2; ++tt) {
    const int tq    = tqs[tt];
    const int i_row = tq * 16 + il;
    float mr = -INFINITY, lr = 0.f;
    float4v oa0 = {0.f,0.f,0.f,0.f}, oa1 = oa0, oa2 = oa0, oa3 = oa0;
    const int nblk = (tq >> 2) + 1;
    for (int jb = 0; jb < nblk; ++jb) {
      const bool diag   = (jb == (tq >> 2));
      const bool skiphi = diag && ((tq & 3) < 2);   // J>=32 all masked
      float s[4][4];
#pragma unroll
      for (int jt = 0; jt < 4; ++jt) {
        if (skiphi && (jt & 1)) continue;           // wave-uniform
        const int rb = jb * 64 + jt * 16 + il;
        short8v kf0 = *(const short8v*)&sm[K_OFF + rb * 64 + ((g ^ (il & 7)) << 3)];
        short8v kf1 = *(const short8v*)&sm[K_OFF + rb * 64 + (((4 + g) ^ (il & 7)) << 3)];
        float4v a = {0.f, 0.f, 0.f, 0.f};
        a = __builtin_amdgcn_mfma_f32_16x16x32_bf16(kf0, qf[tt][0], a, 0, 0, 0);
        a = __builtin_amdgcn_mfma_f32_16x16x32_bf16(kf1, qf[tt][1], a, 0, 0, 0);
        s[jt][0] = a[0]; s[jt][1] = a[1]; s[jt][2] = a[2]; s[jt][3] = a[3];
      }
      // causal mask (diag block only); lane's value (jt,r) has
      // j = jb*64 + (jt&1)*32 + g*8 + (jt>>1)*4 + r
      if (diag) {
#pragma unroll
        for (int jt = 0; jt < 4; ++jt) {
          if (skiphi && (jt & 1)) continue;
          int jb0 = jb * 64 + ((jt & 1) << 5) + (g << 3) + ((jt >> 1) << 2);
#pragma unroll
          for (int r = 0; r < 4; ++r)
            if (jb0 + r > i_row) s[jt][r] = -INFINITY;
        }
      }
      float bm = -INFINITY;
#pragma unroll
      for (int jt = 0; jt < 4; ++jt) {
        if (skiphi && (jt & 1)) continue;
#pragma unroll
        for (int r = 0; r < 4; ++r) bm = fmaxf(bm, s[jt][r]);
      }
      bm = fmaxf(bm, __shfl_xor(bm, 16));
      bm = fmaxf(bm, __shfl_xor(bm, 32));
      const float mn = fmaxf(mr, bm);
      const float rs = exp2f(mr - mn);
      float tot = 0.f;
#pragma unroll
      for (int jt = 0; jt < 4; ++jt) {
        if (skiphi && (jt & 1)) continue;
#pragma unroll
        for (int r = 0; r < 4; ++r) {
          float pv = exp2f(s[jt][r] - mn);
          s[jt][r] = pv;
          tot += pv;
        }
      }
      tot += __shfl_xor(tot, 16);
      tot += __shfl_xor(tot, 32);
      lr = lr * rs + tot;
      mr = mn;
      oa0 *= rs; oa1 *= rs; oa2 *= rs; oa3 *= rs;

      // PV: pf is a pure in-register pack (J spread matches B-frag layout)
      const int nh = skiphi ? 1 : 2;
      for (int half = 0; half < nh; ++half) {
        short8v pf;
#pragma unroll
        for (int r = 0; r < 4; ++r) {
          pf[r]     = f2bf(s[half][r]);
          pf[r + 4] = f2bf(s[half + 2][r]);
        }
        const int cb = jb * 64 + half * 32 + g * 8;
        const int sl = ((cb >> 3) ^ (il & 7)) << 3;
        {
          short8v vf = *(const short8v*)&sm[VT_OFF + (0 * 16 + il) * 256 + sl];
          oa0 = __builtin_amdgcn_mfma_f32_16x16x32_bf16(vf, pf, oa0, 0, 0, 0);
        }
        {
          short8v vf = *(const short8v*)&sm[VT_OFF + (1 * 16 + il) * 256 + sl];
          oa1 = __builtin_amdgcn_mfma_f32_16x16x32_bf16(vf, pf, oa1, 0, 0, 0);
        }
        {
          short8v vf = *(const short8v*)&sm[VT_OFF + (2 * 16 + il) * 256 + sl];
          oa2 = __builtin_amdgcn_mfma_f32_16x16x32_bf16(vf, pf, oa2, 0, 0, 0);
        }
        {
          short8v vf = *(const short8v*)&sm[VT_OFF + (3 * 16 + il) * 256 + sl];
          oa3 = __builtin_amdgcn_mfma_f32_16x16x32_bf16(vf, pf, oa3, 0, 0, 0);
        }
      }
    }
    const float inv = 1.f / lr;
    oa0 *= inv; oa1 *= inv; oa2 *= inv; oa3 *= inv;
    oacc[tt][0] = oa0; oacc[tt][1] = oa1; oacc[tt][2] = oa2; oacc[tt][3] = oa3;
  }

  // ---------- phase 3: transpose O via LDS (swizzled), coalesced store ----------
  __syncthreads();
  float* olds = (float*)sm;             // [256][64] f32, 16B-slot swizzle
#pragma unroll
  for (int tt = 0; tt < 2; ++tt) {
    int i = tqs[tt] * 16 + il;
#pragma unroll
    for (int ht = 0; ht < 4; ++ht)
      *(float4v*)&olds[i * 64 + (((ht * 4 + g) ^ (i & 7)) << 2)] = oacc[tt][ht];
  }
  __syncthreads();
  float* outb = out + (size_t)b * (T_DIM * H_DIM);
#pragma unroll
  for (int k = 0; k < 8; ++k) {
    int idx = k * 512 + tid;
    int row = idx >> 4;
    int sc  = (idx & 15) ^ (row & 7);
    *(float4v*)(outb + idx * 4) = *(const float4v*)&olds[row * 64 + (sc << 2)];
  }
}

extern "C" void kernel_launch(void* const* d_in, const int* in_sizes, int n_in,
                              void* d_out, int out_size, void* d_ws, size_t ws_size,
                              hipStream_t stream) {
  const float* x  = (const float*)d_in[0];
  const float* Wq = (const float*)d_in[1];
  const float* Wk = (const float*)d_in[2];
  const float* Wv = (const float*)d_in[3];
  float* out = (float*)d_out;
  short* wt = (short*)d_ws;   // 48 KB bf16 transposed weights
  prep_w<<<dim3(24), dim3(256), 0, stream>>>(Wq, Wk, Wv, wt);
  (void)hipFuncSetAttribute((const void*)head_fused,
                      hipFuncAttributeMaxDynamicSharedMemorySize, SMEM_BYTES);
  head_fused<<<dim3(1024), dim3(512), SMEM_BYTES, stream>>>(x, wt, out);
}